// Round 12
// baseline (11.363 us; speedup 1.0000x reference)
//
#include <hip/hip_runtime.h>

// NAM inference: B=16384 rows, F=64 features, U=64 units per FeatureNN.
// fnn[b,f] = sum_u clamp((x[b,f]-eb[f])*exp(w[f,u]),0,1)*lw[f,u] + lb[f]
// out[b]   = sum_f fnn[b,f] + bias
// I/O contract (HW-verified round 5): fp32 inputs, dict order;
// d_out fp32 = [out(16384) | fnn(16384x64 row-major)].
//
// R12 = R11 with the DPP ctrl as a template constant (builtin requires a
// compile-time immediate). (a) x-loads hoisted above weight staging.
// (b) row-sum butterfly (ds_bpermute, LDS pipe) replaced by DPP adds on the
// VALU pipe: row_shr 1/2/4/8 + row_bcast:15 + row_bcast:31 -> full wave sum
// lands in lane 63. Inner loop: p*med3(x,0,q), p=lw*e, q=1/e (2 ops/elem).
// Grid: 512 blocks x 256 threads = 2048 waves x 8 rows = 16384 rows exact.

#define NB 16384
#define NF 64
#define NU 64
#define LDP 68   // padded LDS row stride (floats); rows 16B-aligned

template <int CTRL>
__device__ __forceinline__ float dpp_add(float s) {
    int d = __builtin_amdgcn_update_dpp(
        0, __builtin_bit_cast(int, s), CTRL, 0xf, 0xf, true);
    return s + __builtin_bit_cast(float, d);
}

__global__ __launch_bounds__(256, 2) void nam_reg(
    const float* __restrict__ x,
    const float* __restrict__ exu_w,
    const float* __restrict__ exu_b,
    const float* __restrict__ lin_w,
    const float* __restrict__ lin_b,
    const float* __restrict__ bias,
    float* __restrict__ out,
    float* __restrict__ fnn) {

    __shared__ float pws[NF * LDP];   // p = lw * exp(w)
    __shared__ float qws[NF * LDP];   // q = 1 / exp(w)

    const int t = threadIdx.x;
    const int lane = t & 63;
    const int wid = (blockIdx.x * 256 + t) >> 6;   // 0..2047
    const int rbase = wid * 8;

    // --- Issue x loads FIRST (independent of staging; latency hides under it).
    float xv[8];
#pragma unroll
    for (int j = 0; j < 8; ++j) xv[j] = x[(size_t)(rbase + j) * NF + lane];

    const float eb = exu_b[lane];
    const float lb = lin_b[lane];
    const float b0 = bias[0];

    // --- Stage: coalesced float4 loads of both tables (layout already [f][u]),
    // --- compute p,q, float4 stores to padded LDS.
#pragma unroll
    for (int k = 0; k < 4; ++k) {
        int g = (k * 256 + t) * 4;              // 4 consecutive source floats
        float4 a = *(const float4*)(exu_w + g);
        float4 b = *(const float4*)(lin_w + g);
        int f = g >> 6;
        int u = g & 63;
        float e0 = __expf(a.x), e1 = __expf(a.y), e2 = __expf(a.z), e3 = __expf(a.w);
        *(float4*)&pws[f * LDP + u] = make_float4(b.x * e0, b.y * e1, b.z * e2, b.w * e3);
        *(float4*)&qws[f * LDP + u] = make_float4(__builtin_amdgcn_rcpf(e0),
                                                  __builtin_amdgcn_rcpf(e1),
                                                  __builtin_amdgcn_rcpf(e2),
                                                  __builtin_amdgcn_rcpf(e3));
    }

    __syncthreads();

    // --- Fill this lane's feature row into registers: 16+16 ds_read_b128.
    float p[NU], q[NU];
    {
        const float4* pr = (const float4*)&pws[lane * LDP];
        const float4* qr = (const float4*)&qws[lane * LDP];
#pragma unroll
        for (int k = 0; k < NU / 4; ++k) {
            float4 pv = pr[k];
            float4 qv = qr[k];
            p[4*k+0] = pv.x; p[4*k+1] = pv.y; p[4*k+2] = pv.z; p[4*k+3] = pv.w;
            q[4*k+0] = qv.x; q[4*k+1] = qv.y; q[4*k+2] = qv.z; q[4*k+3] = qv.w;
        }
    }

    float acc[8];
#pragma unroll
    for (int j = 0; j < 8; ++j) {
        xv[j] -= eb;
        acc[j] = 0.0f;
    }

    // --- Pure-VALU u-loop: 8 independent chains, 2 ops per (b,f,u).
#pragma unroll
    for (int u = 0; u < NU; ++u) {
        const float pu = p[u], qu = q[u];
#pragma unroll
        for (int j = 0; j < 8; ++j) {
            acc[j] = __builtin_fmaf(pu, __builtin_amdgcn_fmed3f(xv[j], 0.f, qu), acc[j]);
        }
    }

    // --- Epilogue: + lin_b, coalesced fnn stores, DPP row-sums (VALU pipe).
    float s[8];
#pragma unroll
    for (int j = 0; j < 8; ++j) {
        float a = acc[j] + lb;
        fnn[(size_t)(rbase + j) * NF + lane] = a;
        s[j] = a;
    }
#pragma unroll
    for (int j = 0; j < 8; ++j) {
        s[j] = dpp_add<0x111>(s[j]);   // row_shr:1
        s[j] = dpp_add<0x112>(s[j]);   // row_shr:2
        s[j] = dpp_add<0x114>(s[j]);   // row_shr:4
        s[j] = dpp_add<0x118>(s[j]);   // row_shr:8  -> lanes 15/31/47/63 = row sums
        s[j] = dpp_add<0x142>(s[j]);   // row_bcast:15 -> lane31 += R0.., lane63 += R2..
        s[j] = dpp_add<0x143>(s[j]);   // row_bcast:31 -> lane63 = full sum
    }
    if (lane == 63) {
        *(float4*)(out + rbase)     = make_float4(s[0] + b0, s[1] + b0, s[2] + b0, s[3] + b0);
        *(float4*)(out + rbase + 4) = make_float4(s[4] + b0, s[5] + b0, s[6] + b0, s[7] + b0);
    }
}

extern "C" void kernel_launch(void* const* d_in, const int* in_sizes, int n_in,
                              void* d_out, int out_size, void* d_ws, size_t ws_size,
                              hipStream_t stream) {
    const float* x     = (const float*)d_in[0];
    const float* exu_w = (const float*)d_in[1];
    const float* exu_b = (const float*)d_in[2];
    const float* lin_w = (const float*)d_in[3];
    const float* lin_b = (const float*)d_in[4];
    const float* bias  = (const float*)d_in[5];

    float* out = (float*)d_out;
    float* fnn = out + NB;

    // 2048 waves total: 512 blocks x 4 waves/block, 8 rows/wave = 16384 rows.
    nam_reg<<<dim3(512), dim3(256), 0, stream>>>(
        x, exu_w, exu_b, lin_w, lin_b, bias, out, fnn);
}

// Round 13
// 11.357 us; speedup vs baseline: 1.0006x; 1.0006x over previous
//
#include <hip/hip_runtime.h>

// NAM inference: B=16384 rows, F=64 features, U=64 units per FeatureNN.
// fnn[b,f] = sum_u clamp((x[b,f]-eb[f])*exp(w[f,u]),0,1)*lw[f,u] + lb[f]
// out[b]   = sum_f fnn[b,f] + bias
// I/O contract (HW-verified round 5): fp32 inputs, dict order;
// d_out fp32 = [out(16384) | fnn(16384x64 row-major)].
//
// R13: 512-thread blocks (256 blocks = 1/CU) -> stage redundancy halved
// (each block re-reads the 32KB weight table once; fewer blocks = less
// chip-wide L2 traffic + transcendentals). Stage global loads issued FIRST
// (they gate the barrier); x-loads second (latency hides under stage+fill).
// Inner loop: p*med3(x,0,q), p=lw*e, q=1/e (2 VALU ops/elem, register-held
// weights). Row-sum: DPP adds on VALU pipe (verified R12). 8 rows/wave.
// Grid: 256 blocks x 8 waves x 8 rows = 16384 rows exact.

#define NB 16384
#define NF 64
#define NU 64
#define LDP 68   // padded LDS row stride (floats); rows 16B-aligned

template <int CTRL>
__device__ __forceinline__ float dpp_add(float s) {
    int d = __builtin_amdgcn_update_dpp(
        0, __builtin_bit_cast(int, s), CTRL, 0xf, 0xf, true);
    return s + __builtin_bit_cast(float, d);
}

__global__ __launch_bounds__(512, 2) void nam_reg(
    const float* __restrict__ x,
    const float* __restrict__ exu_w,
    const float* __restrict__ exu_b,
    const float* __restrict__ lin_w,
    const float* __restrict__ lin_b,
    const float* __restrict__ bias,
    float* __restrict__ out,
    float* __restrict__ fnn) {

    __shared__ float pws[NF * LDP];   // p = lw * exp(w)
    __shared__ float qws[NF * LDP];   // q = 1 / exp(w)

    const int t = threadIdx.x;
    const int lane = t & 63;
    const int wid = blockIdx.x * 8 + (t >> 6);   // 0..2047
    const int rbase = wid * 8;

    // --- (1) Stage global loads FIRST: they gate the barrier.
    // 512 threads x 2 float4 cover each 4096-float table.
    const int g0 = t * 4;
    const int g1 = (512 + t) * 4;
    float4 wa0 = *(const float4*)(exu_w + g0);
    float4 la0 = *(const float4*)(lin_w + g0);
    float4 wa1 = *(const float4*)(exu_w + g1);
    float4 la1 = *(const float4*)(lin_w + g1);

    // --- (2) x-loads second: not needed until after barrier+fill.
    float xv[8];
#pragma unroll
    for (int j = 0; j < 8; ++j) xv[j] = x[(size_t)(rbase + j) * NF + lane];

    const float eb = exu_b[lane];
    const float lb = lin_b[lane];
    const float b0 = bias[0];

    // --- (3) Compute p,q and write padded LDS (float4 = ds_write_b128).
    {
        int f = g0 >> 6, u = g0 & 63;
        float e0 = __expf(wa0.x), e1 = __expf(wa0.y),
              e2 = __expf(wa0.z), e3 = __expf(wa0.w);
        *(float4*)&pws[f * LDP + u] = make_float4(la0.x * e0, la0.y * e1,
                                                  la0.z * e2, la0.w * e3);
        *(float4*)&qws[f * LDP + u] = make_float4(__builtin_amdgcn_rcpf(e0),
                                                  __builtin_amdgcn_rcpf(e1),
                                                  __builtin_amdgcn_rcpf(e2),
                                                  __builtin_amdgcn_rcpf(e3));
    }
    {
        int f = g1 >> 6, u = g1 & 63;
        float e0 = __expf(wa1.x), e1 = __expf(wa1.y),
              e2 = __expf(wa1.z), e3 = __expf(wa1.w);
        *(float4*)&pws[f * LDP + u] = make_float4(la1.x * e0, la1.y * e1,
                                                  la1.z * e2, la1.w * e3);
        *(float4*)&qws[f * LDP + u] = make_float4(__builtin_amdgcn_rcpf(e0),
                                                  __builtin_amdgcn_rcpf(e1),
                                                  __builtin_amdgcn_rcpf(e2),
                                                  __builtin_amdgcn_rcpf(e3));
    }

    __syncthreads();

    // --- (4) Fill this lane's feature row into registers: 16+16 ds_read_b128.
    float p[NU], q[NU];
    {
        const float4* pr = (const float4*)&pws[lane * LDP];
        const float4* qr = (const float4*)&qws[lane * LDP];
#pragma unroll
        for (int k = 0; k < NU / 4; ++k) {
            float4 pv = pr[k];
            float4 qv = qr[k];
            p[4*k+0] = pv.x; p[4*k+1] = pv.y; p[4*k+2] = pv.z; p[4*k+3] = pv.w;
            q[4*k+0] = qv.x; q[4*k+1] = qv.y; q[4*k+2] = qv.z; q[4*k+3] = qv.w;
        }
    }

    float acc[8];
#pragma unroll
    for (int j = 0; j < 8; ++j) {
        xv[j] -= eb;
        acc[j] = 0.0f;
    }

    // --- (5) Pure-VALU u-loop: 8 independent chains, 2 ops per (b,f,u).
#pragma unroll
    for (int u = 0; u < NU; ++u) {
        const float pu = p[u], qu = q[u];
#pragma unroll
        for (int j = 0; j < 8; ++j) {
            acc[j] = __builtin_fmaf(pu, __builtin_amdgcn_fmed3f(xv[j], 0.f, qu), acc[j]);
        }
    }

    // --- (6) Epilogue: + lin_b, coalesced fnn stores, DPP row-sums.
    float s[8];
#pragma unroll
    for (int j = 0; j < 8; ++j) {
        float a = acc[j] + lb;
        fnn[(size_t)(rbase + j) * NF + lane] = a;
        s[j] = a;
    }
#pragma unroll
    for (int j = 0; j < 8; ++j) {
        s[j] = dpp_add<0x111>(s[j]);   // row_shr:1
        s[j] = dpp_add<0x112>(s[j]);   // row_shr:2
        s[j] = dpp_add<0x114>(s[j]);   // row_shr:4
        s[j] = dpp_add<0x118>(s[j]);   // row_shr:8  -> lanes 15/31/47/63
        s[j] = dpp_add<0x142>(s[j]);   // row_bcast:15
        s[j] = dpp_add<0x143>(s[j]);   // row_bcast:31 -> lane63 = full sum
    }
    if (lane == 63) {
        *(float4*)(out + rbase)     = make_float4(s[0] + b0, s[1] + b0, s[2] + b0, s[3] + b0);
        *(float4*)(out + rbase + 4) = make_float4(s[4] + b0, s[5] + b0, s[6] + b0, s[7] + b0);
    }
}

extern "C" void kernel_launch(void* const* d_in, const int* in_sizes, int n_in,
                              void* d_out, int out_size, void* d_ws, size_t ws_size,
                              hipStream_t stream) {
    const float* x     = (const float*)d_in[0];
    const float* exu_w = (const float*)d_in[1];
    const float* exu_b = (const float*)d_in[2];
    const float* lin_w = (const float*)d_in[3];
    const float* lin_b = (const float*)d_in[4];
    const float* bias  = (const float*)d_in[5];

    float* out = (float*)d_out;
    float* fnn = out + NB;

    // 256 blocks x 8 waves/block x 8 rows/wave = 16384 rows exact (1 block/CU).
    nam_reg<<<dim3(256), dim3(512), 0, stream>>>(
        x, exu_w, exu_b, lin_w, lin_b, bias, out, fnn);
}